// Round 10
// baseline (258.260 us; speedup 1.0000x reference)
//
#include <hip/hip_runtime.h>

#define NDIM 512
#define NN (512*512)

typedef float          fv4  __attribute__((ext_vector_type(4)));
typedef unsigned int   uv2  __attribute__((ext_vector_type(2)));
typedef unsigned int   uv4  __attribute__((ext_vector_type(4)));
typedef unsigned short usv4 __attribute__((ext_vector_type(4)));
typedef unsigned short usv8 __attribute__((ext_vector_type(8)));
typedef short          sv8  __attribute__((ext_vector_type(8)));

__device__ __forceinline__ unsigned short f2bf(float x){
    unsigned u = __builtin_bit_cast(unsigned, x);
    u += 0x7fffu + ((u >> 16) & 1u);          // round-to-nearest-even
    return (unsigned short)(u >> 16);
}
__device__ __forceinline__ float bf2f(unsigned short s){
    unsigned u = ((unsigned)s) << 16;
    return __builtin_bit_cast(float, u);
}
__device__ __forceinline__ usv8 cvt8(fv4 a, fv4 b){
    usv8 r;
    #pragma unroll
    for (int j = 0; j < 4; ++j) { r[j] = f2bf(a[j]); r[4 + j] = f2bf(b[j]); }
    return r;
}

// D += A*B, bf16 16x16x32 (builtin; short8 = 8 bf16 per operand)
#define MFMA16(acc, va, vb) \
    acc = __builtin_amdgcn_mfma_f32_16x16x32_bf16( \
        __builtin_bit_cast(sv8, va), __builtin_bit_cast(sv8, vb), acc, 0, 0, 0)

// hardware transpose read: 16-lane cluster reads its contiguous 128B subtile
// (addr(l) = base + 8*l B); lane l receives elems (l&15) + j*16 + (l>>4)*64
#define TRREAD(dst, addr) \
    asm volatile("ds_read_b64_tr_b16 %0, %1" : "=v"(dst) : "v"(addr))

// ---------------- pre-convert: a_o -> hi/lo bf16 (A only; 67 MB not 268) ----
__global__ __launch_bounds__(256) void aconv_kernel(
    const float* __restrict__ a_o,
    unsigned short* __restrict__ Ah, unsigned short* __restrict__ Al)
{
    const int b  = blockIdx.y;
    const int e0 = blockIdx.x * 2048 + threadIdx.x * 8;
    float4 v0 = *(const float4*)(a_o + b * NN + e0);
    float4 v1 = *(const float4*)(a_o + b * NN + e0 + 4);
    float vv[8] = {v0.x, v0.y, v0.z, v0.w, v1.x, v1.y, v1.z, v1.w};
    usv8 h, l;
    #pragma unroll
    for (int j = 0; j < 8; ++j) {
        unsigned short hb = f2bf(vv[j]);
        h[j] = hb;
        l[j] = f2bf(vv[j] - bf2f(hb));
    }
    *(usv8*)(Ah + b * NN + e0) = h;
    *(usv8*)(Al + b * NN + e0) = l;
}

// ---- unified GEMM kernel: double-buffered LDS, T14 split staging -----------
// stage==0: grid (4,4,8)  all blocks SPLIT: AA = A@A (fp32 + hi/lo bf16 out)
// stage==1: grid (4,4,40) z<8 SPLIT: AAA = A@AA (fp32)
//                         z>=8 MIX : MIXbf[z-8] = bf16(S@A + A@S), S from f32
__global__ __launch_bounds__(256) void gemm_fused_kernel(
    const float* __restrict__ s_f32,
    const unsigned short* __restrict__ Ah, const unsigned short* __restrict__ Al,
    unsigned short* __restrict__ AAh, unsigned short* __restrict__ AAl,
    float* __restrict__ AA, float* __restrict__ AAA,
    unsigned short* __restrict__ MIXbf, int stage)
{
    const int z = blockIdx.z;
    const bool split = (stage == 0) || (z < 8);

    const unsigned short *X1 = nullptr, *X2, *Y1, *Y2 = nullptr;
    const float *SX = nullptr;            // mix: S operand (f32), rows and cols
    if (stage == 0)      { X1 = Ah + z * NN;  X2 = Al + z * NN;
                           Y1 = Ah + z * NN;  Y2 = Al + z * NN; }
    else if (z < 8)      { X1 = Ah + z * NN;  X2 = Al + z * NN;
                           Y1 = AAh + z * NN; Y2 = AAl + z * NN; }
    else                 { const int z2 = z - 8, b = z2 & 7;
                           SX = s_f32 + z2 * NN;   // X1 (rows) and Y2 (cols)
                           X2 = Ah + b * NN;
                           Y1 = Ah + b * NN; }

    const int row0 = blockIdx.y * 128, col0 = blockIdx.x * 128;
    const int tid = threadIdx.x, lane = tid & 63, w = tid >> 6;

    __shared__ unsigned short Xa[2][128][40], Xb[2][128][40];
    __shared__ unsigned short Ba[2][4096], Bb[2][4096];

    fv4 acc[4][4];
    #pragma unroll
    for (int mi = 0; mi < 4; ++mi)
        #pragma unroll
        for (int ni = 0; ni < 4; ++ni) acc[mi][ni] = (fv4)0.f;

    // ---- per-thread staging geometry (identical mappings to round 8) ----
    const int xr  = tid >> 2, xc = (tid & 3) << 3;
    const int xo0 = (row0 + xr) * NDIM + xc;
    const int xo1 = xo0 + 64 * NDIM;
    const int kl = tid & 3, hh = (tid >> 2) & 1, cs = (tid >> 3) & 7, kh = tid >> 6;
    const int kb0 = kh * 4 + kl;
    const int yo0 = kb0 * NDIM + col0 + cs * 16 + hh * 8;
    const int yo1 = yo0 + 16 * NDIM;
    const int lb0 = cs * 512 + kb0 * 16 + hh * 8;
    const int lb1 = lb0 + 256;

    const unsigned laneoff = (((unsigned)lane >> 4) << 7) | (((unsigned)lane & 15) << 3);
    const unsigned wcol    = ((unsigned)(w & 1)) << 12;
    const int g4 = (lane >> 4) * 4;

    usv8 lx1a, lx1b, lx2a, lx2b, ly1a, ly1b, ly2a, ly2b;
    fv4 fx1a0, fx1a1, fx1b0, fx1b1, fy2a0, fy2a1, fy2b0, fy2b1;

    auto gload = [&](int k0) {
        if (split) {
            lx1a = *(const usv8*)(X1 + xo0 + k0);
            lx1b = *(const usv8*)(X1 + xo1 + k0);
            ly2a = *(const usv8*)(Y2 + yo0 + k0 * NDIM);
            ly2b = *(const usv8*)(Y2 + yo1 + k0 * NDIM);
        } else {
            fx1a0 = *(const fv4*)(SX + xo0 + k0);
            fx1a1 = *(const fv4*)(SX + xo0 + k0 + 4);
            fx1b0 = *(const fv4*)(SX + xo1 + k0);
            fx1b1 = *(const fv4*)(SX + xo1 + k0 + 4);
            fy2a0 = *(const fv4*)(SX + yo0 + k0 * NDIM);
            fy2a1 = *(const fv4*)(SX + yo0 + k0 * NDIM + 4);
            fy2b0 = *(const fv4*)(SX + yo1 + k0 * NDIM);
            fy2b1 = *(const fv4*)(SX + yo1 + k0 * NDIM + 4);
        }
        lx2a = *(const usv8*)(X2 + xo0 + k0);
        lx2b = *(const usv8*)(X2 + xo1 + k0);
        ly1a = *(const usv8*)(Y1 + yo0 + k0 * NDIM);
        ly1b = *(const usv8*)(Y1 + yo1 + k0 * NDIM);
    };
    auto swrite = [&](int buf) {
        if (split) {
            *(usv8*)&Xa[buf][xr][xc]      = lx1a;
            *(usv8*)&Xa[buf][64 + xr][xc] = lx1b;
            *(usv8*)&Bb[buf][lb0] = ly2a;
            *(usv8*)&Bb[buf][lb1] = ly2b;
        } else {
            *(usv8*)&Xa[buf][xr][xc]      = cvt8(fx1a0, fx1a1);
            *(usv8*)&Xa[buf][64 + xr][xc] = cvt8(fx1b0, fx1b1);
            *(usv8*)&Bb[buf][lb0] = cvt8(fy2a0, fy2a1);
            *(usv8*)&Bb[buf][lb1] = cvt8(fy2b0, fy2b1);
        }
        *(usv8*)&Xb[buf][xr][xc]      = lx2a;
        *(usv8*)&Xb[buf][64 + xr][xc] = lx2b;
        *(usv8*)&Ba[buf][lb0] = ly1a;
        *(usv8*)&Ba[buf][lb1] = ly1b;
    };
    auto compute = [&](int buf) {
        const unsigned ba_base = (unsigned)(uintptr_t)&Ba[buf][0];
        const unsigned bb_base = (unsigned)(uintptr_t)&Bb[buf][0];
        uv2 fa[4][2], fb[4][2];
        #pragma unroll
        for (int ni = 0; ni < 4; ++ni)
            #pragma unroll
            for (int h = 0; h < 2; ++h) {
                TRREAD(fa[ni][h], ba_base + wcol + laneoff + ni * 1024 + h * 512);
                TRREAD(fb[ni][h], bb_base + wcol + laneoff + ni * 1024 + h * 512);
            }
        asm volatile("s_waitcnt lgkmcnt(0)" ::: "memory");
        __builtin_amdgcn_sched_barrier(0);

        #pragma unroll
        for (int mi = 0; mi < 4; ++mi) {
            const unsigned short* xr1 = &Xa[buf][(w >> 1) * 64 + mi * 16 + (lane & 15)][0];
            const unsigned short* xr2 = &Xb[buf][(w >> 1) * 64 + mi * 16 + (lane & 15)][0];
            uv2 a0 = *(const uv2*)(xr1 + g4);
            uv2 a1 = *(const uv2*)(xr1 + 16 + g4);
            uv2 b0 = *(const uv2*)(xr2 + g4);
            uv2 b1 = *(const uv2*)(xr2 + 16 + g4);
            uv4 xva = {a0.x, a0.y, a1.x, a1.y};
            uv4 xvb = {b0.x, b0.y, b1.x, b1.y};
            #pragma unroll
            for (int ni = 0; ni < 4; ++ni) {
                uv4 vba = {fa[ni][0].x, fa[ni][0].y, fa[ni][1].x, fa[ni][1].y};
                uv4 vbb = {fb[ni][0].x, fb[ni][0].y, fb[ni][1].x, fb[ni][1].y};
                if (split) {
                    MFMA16(acc[mi][ni], xva, vba);   // hi*hi  (X1 @ Y1)
                    MFMA16(acc[mi][ni], xva, vbb);   // hi*lo  (X1 @ Y2)
                    MFMA16(acc[mi][ni], xvb, vba);   // lo*hi  (X2 @ Y1)
                } else {
                    MFMA16(acc[mi][ni], xva, vba);   // S@A  (Xa=S, Ba=A)
                    MFMA16(acc[mi][ni], xvb, vbb);   // A@S  (Xb=A, Bb=S)
                }
            }
        }
    };

    // ---- 2-phase pipeline: one barrier per K-step ----
    gload(0);
    swrite(0);
    __syncthreads();
    int cur = 0;
    for (int t = 0; t < 15; ++t) {
        gload((t + 1) * 32);     // issue early (T14): latency hides under compute
        compute(cur);
        swrite(cur ^ 1);         // vmcnt drain happens here, after compute
        __syncthreads();         // single barrier: writers touched the idle buffer
        cur ^= 1;
    }
    compute(cur);

    const int g = lane >> 4, c15 = lane & 15;
    if (split) {
        float* C = (stage == 0) ? (AA + z * NN) : (AAA + z * NN);
        #pragma unroll
        for (int mi = 0; mi < 4; ++mi)
            #pragma unroll
            for (int ni = 0; ni < 4; ++ni) {
                int r = row0 + (w >> 1) * 64 + mi * 16 + g * 4;
                int c = col0 + (w & 1) * 64 + ni * 16 + c15;
                #pragma unroll
                for (int q = 0; q < 4; ++q) {
                    float v = acc[mi][ni][q];
                    C[(r + q) * NDIM + c] = v;
                    if (stage == 0) {
                        unsigned short hb = f2bf(v);
                        AAh[z * NN + (r + q) * NDIM + c] = hb;
                        AAl[z * NN + (r + q) * NDIM + c] = f2bf(v - bf2f(hb));
                    }
                }
            }
    } else {
        unsigned short* Cm = MIXbf + (z - 8) * NN;
        #pragma unroll
        for (int mi = 0; mi < 4; ++mi)
            #pragma unroll
            for (int ni = 0; ni < 4; ++ni) {
                int r = row0 + (w >> 1) * 64 + mi * 16 + g * 4;
                int c = col0 + (w & 1) * 64 + ni * 16 + c15;
                #pragma unroll
                for (int q = 0; q < 4; ++q)
                    Cm[(r + q) * NDIM + c] = f2bf(acc[mi][ni][q]);
            }
    }
}

// ---------------- Combine: temp[o,b,n,m] + per-(o,b) max-abs ----------------
// 8 elems/thread, grid (128, 8). use_tmp: store bf16 pre-norm tmp, else fp32 out.
__global__ __launch_bounds__(256) void combine_kernel(
    const float* __restrict__ s_f32, const unsigned short* __restrict__ Ah,
    const float* __restrict__ AA, const float* __restrict__ AAA,
    const unsigned short* __restrict__ MIXbf,
    const float* __restrict__ alpha, const float* __restrict__ beta,
    const float* __restrict__ coeffs,
    float* __restrict__ out, unsigned short* __restrict__ tmp,
    unsigned int* __restrict__ smax, int use_tmp)
{
    const int b  = blockIdx.y;
    const int e0 = blockIdx.x * 2048 + threadIdx.x * 8;
    const int n  = e0 >> 9;
    const int m0 = e0 & 511;

    float ca[8], cb[8], cc[8];
    #pragma unroll
    for (int o = 0; o < 8; ++o) {
        float c1 = 0.f, c2 = 0.f, c3 = 0.f;
        #pragma unroll
        for (int i = 0; i < 4; ++i) {
            c1 += coeffs[o * 16 + 4 + i];
            c2 += coeffs[o * 16 + 8 + i];
            c3 += coeffs[o * 16 + 12 + i];
        }
        ca[o] = c1 - 3.f * c3; cb[o] = 2.f * c2; cc[o] = 4.f * c3;
    }

    float av[8], aav[8], aaav[8], sv[4][8], mv[4][8];
    {
        usv8 a8 = *(const usv8*)(Ah + b * NN + e0);
        #pragma unroll
        for (int j = 0; j < 8; ++j) av[j] = bf2f(a8[j]);
        const float4 q0 = *(const float4*)(AA + b * NN + e0);
        const float4 q1 = *(const float4*)(AA + b * NN + e0 + 4);
        aav[0]=q0.x; aav[1]=q0.y; aav[2]=q0.z; aav[3]=q0.w;
        aav[4]=q1.x; aav[5]=q1.y; aav[6]=q1.z; aav[7]=q1.w;
        const float4 r0 = *(const float4*)(AAA + b * NN + e0);
        const float4 r1 = *(const float4*)(AAA + b * NN + e0 + 4);
        aaav[0]=r0.x; aaav[1]=r0.y; aaav[2]=r0.z; aaav[3]=r0.w;
        aaav[4]=r1.x; aaav[5]=r1.y; aaav[6]=r1.z; aaav[7]=r1.w;
        #pragma unroll
        for (int i = 0; i < 4; ++i) {
            const float4 s0 = *(const float4*)(s_f32 + (i * 8 + b) * NN + e0);
            const float4 s1 = *(const float4*)(s_f32 + (i * 8 + b) * NN + e0 + 4);
            sv[i][0]=s0.x; sv[i][1]=s0.y; sv[i][2]=s0.z; sv[i][3]=s0.w;
            sv[i][4]=s1.x; sv[i][5]=s1.y; sv[i][6]=s1.z; sv[i][7]=s1.w;
            usv8 m8 = *(const usv8*)(MIXbf + (i * 8 + b) * NN + e0);
            #pragma unroll
            for (int j = 0; j < 8; ++j) mv[i][j] = bf2f(m8[j]);
        }
    }

    float lmax[8];
    #pragma unroll
    for (int o = 0; o < 8; ++o) {
        float outv[8];
        float lm = 0.f;
        #pragma unroll
        for (int j = 0; j < 8; ++j) {
            float t = ca[o] * av[j] + cb[o] * aav[j] + cc[o] * aaav[j];
            #pragma unroll
            for (int i = 0; i < 4; ++i)
                t += alpha[o * 4 + i] * sv[i][j] + beta[o * 4 + i] * mv[i][j];
            t *= 0.25f;
            if (n == m0 + j) t = 0.f;
            outv[j] = t;
            lm = fmaxf(lm, fabsf(t));
        }
        lmax[o] = lm;
        if (use_tmp) {
            usv8 ov;
            #pragma unroll
            for (int j = 0; j < 8; ++j) ov[j] = f2bf(outv[j]);
            *(usv8*)(tmp + (o * 8 + b) * NN + e0) = ov;
        } else {
            *(float4*)(out + (o * 8 + b) * NN + e0) =
                make_float4(outv[0], outv[1], outv[2], outv[3]);
            *(float4*)(out + (o * 8 + b) * NN + e0 + 4) =
                make_float4(outv[4], outv[5], outv[6], outv[7]);
        }
    }

    #pragma unroll
    for (int o = 0; o < 8; ++o) {
        #pragma unroll
        for (int off = 32; off > 0; off >>= 1)
            lmax[o] = fmaxf(lmax[o], __shfl_xor(lmax[o], off, 64));
    }
    __shared__ float red[4][8];
    const int lane = threadIdx.x & 63, wv = threadIdx.x >> 6;
    if (lane == 0) {
        #pragma unroll
        for (int o = 0; o < 8; ++o) red[wv][o] = lmax[o];
    }
    __syncthreads();
    if (threadIdx.x < 8) {
        const int o = threadIdx.x;
        const float mfin = fmaxf(fmaxf(red[0][o], red[1][o]), fmaxf(red[2][o], red[3][o]));
        atomicMax(&smax[o * 8 + b], __float_as_uint(mfin));
    }
}

// ---------------- Normalize + relu -> fp32 out ----------------
// 8 elems/thread, grid (128, 64)
__global__ __launch_bounds__(256) void norm_kernel(
    float* __restrict__ out, const unsigned short* __restrict__ tmp,
    const unsigned int* __restrict__ smax, const float* __restrict__ tau,
    int use_tmp)
{
    const int ob = blockIdx.y;
    const float mx = __uint_as_float(smax[ob]);
    const float inv = (mx == 0.f) ? 1.f : (1.f / mx);
    const float t = tau[ob >> 3];
    const int e0 = blockIdx.x * 2048 + threadIdx.x * 8;
    float v[8];
    if (use_tmp) {
        usv8 tv = *(const usv8*)(tmp + ob * NN + e0);
        #pragma unroll
        for (int j = 0; j < 8; ++j) v[j] = bf2f(tv[j]);
    } else {
        float4 v0 = *(float4*)(out + ob * NN + e0);
        float4 v1 = *(float4*)(out + ob * NN + e0 + 4);
        v[0]=v0.x; v[1]=v0.y; v[2]=v0.z; v[3]=v0.w;
        v[4]=v1.x; v[5]=v1.y; v[6]=v1.z; v[7]=v1.w;
    }
    #pragma unroll
    for (int j = 0; j < 8; ++j) v[j] = fmaxf(fmaf(v[j], inv, -t), 0.f);
    *(float4*)(out + ob * NN + e0)     = make_float4(v[0], v[1], v[2], v[3]);
    *(float4*)(out + ob * NN + e0 + 4) = make_float4(v[4], v[5], v[6], v[7]);
}

extern "C" void kernel_launch(void* const* d_in, const int* in_sizes, int n_in,
                              void* d_out, int out_size, void* d_ws, size_t ws_size,
                              hipStream_t stream) {
    (void)in_sizes; (void)n_in; (void)out_size;
    const float* s_in   = (const float*)d_in[0];  // (4,8,512,512)
    const float* a_o    = (const float*)d_in[1];  // (8,512,512)
    const float* alpha  = (const float*)d_in[2];  // (8,4)
    const float* beta   = (const float*)d_in[3];  // (8,4)
    const float* coeffs = (const float*)d_in[4];  // (8,4,4)
    const float* tau    = (const float*)d_in[5];  // (8)
    float* out = (float*)d_out;                   // (8,8,512,512)

    // workspace layout (no s_bf anymore)
    float* AA  = (float*)d_ws;                       // 8NN f32
    float* AAA = AA + 8 * NN;                        // 8NN f32
    unsigned short* Ah    = (unsigned short*)(AAA + 8 * NN);  // 8NN bf16
    unsigned short* Al    = Ah + 8 * NN;             // 8NN
    unsigned short* AAh   = Al + 8 * NN;             // 8NN
    unsigned short* AAl   = AAh + 8 * NN;            // 8NN
    unsigned short* MIXbf = AAl + 8 * NN;            // 32NN
    unsigned int* SMAX = (unsigned int*)(MIXbf + 32 * NN);    // 64
    unsigned short* TMP = (unsigned short*)(SMAX + 64);       // 64NN (optional)

    const size_t need_tmp = (size_t)((char*)(TMP + 64 * NN) - (char*)d_ws);
    const int use_tmp = (ws_size >= need_tmp) ? 1 : 0;

    hipLaunchKernelGGL(aconv_kernel, dim3(128, 8), dim3(256), 0, stream,
                       a_o, Ah, Al);
    hipLaunchKernelGGL(gemm_fused_kernel, dim3(4, 4, 8), dim3(256), 0, stream,
                       s_in, Ah, Al, AAh, AAl, AA, AAA, MIXbf, 0);   // AA
    hipLaunchKernelGGL(gemm_fused_kernel, dim3(4, 4, 40), dim3(256), 0, stream,
                       s_in, Ah, Al, AAh, AAl, AA, AAA, MIXbf, 1);   // AAA + MIX
    hipMemsetAsync(SMAX, 0, 64 * sizeof(unsigned int), stream);
    hipLaunchKernelGGL(combine_kernel, dim3(128, 8), dim3(256), 0, stream,
                       s_in, Ah, AA, AAA, MIXbf, alpha, beta, coeffs,
                       out, TMP, SMAX, use_tmp);
    hipLaunchKernelGGL(norm_kernel, dim3(128, 64), dim3(256), 0, stream,
                       out, TMP, SMAX, tau, use_tmp);
}

// Round 11
// 213.489 us; speedup vs baseline: 1.2097x; 1.2097x over previous
//
#include <hip/hip_runtime.h>

#define NDIM 512
#define NN (512*512)

typedef float          fv4  __attribute__((ext_vector_type(4)));
typedef unsigned int   uv2  __attribute__((ext_vector_type(2)));
typedef unsigned int   uv4  __attribute__((ext_vector_type(4)));
typedef unsigned short usv4 __attribute__((ext_vector_type(4)));
typedef unsigned short usv8 __attribute__((ext_vector_type(8)));
typedef short          sv8  __attribute__((ext_vector_type(8)));

__device__ __forceinline__ unsigned short f2bf(float x){
    unsigned u = __builtin_bit_cast(unsigned, x);
    u += 0x7fffu + ((u >> 16) & 1u);          // round-to-nearest-even
    return (unsigned short)(u >> 16);
}
__device__ __forceinline__ float bf2f(unsigned short s){
    unsigned u = ((unsigned)s) << 16;
    return __builtin_bit_cast(float, u);
}

// D += A*B, bf16 16x16x32 (builtin; short8 = 8 bf16 per operand)
#define MFMA16(acc, va, vb) \
    acc = __builtin_amdgcn_mfma_f32_16x16x32_bf16( \
        __builtin_bit_cast(sv8, va), __builtin_bit_cast(sv8, vb), acc, 0, 0, 0)

// hardware transpose read: 16-lane cluster reads its contiguous 128B subtile
// (addr(l) = base + 8*l B); lane l receives elems (l&15) + j*16 + (l>>4)*64
#define TRREAD(dst, addr) \
    asm volatile("ds_read_b64_tr_b16 %0, %1" : "=v"(dst) : "v"(addr))

// ---------------- pre-convert: s_in -> bf16, a_o -> hi/lo bf16 --------------
// total traffic ~67 MB (~12 us) — r9/r10 showed removing this is a net loss.
__global__ __launch_bounds__(256) void preconv_kernel(
    const float* __restrict__ s_in, const float* __restrict__ a_o,
    unsigned short* __restrict__ s_bf, unsigned short* __restrict__ Ah,
    unsigned short* __restrict__ Al)
{
    const int z  = blockIdx.y;
    const int e0 = blockIdx.x * 1024 + threadIdx.x * 4;
    if (z < 32) {
        float4 v = *(const float4*)(s_in + z * NN + e0);
        float vv[4] = {v.x, v.y, v.z, v.w};
        usv4 o;
        #pragma unroll
        for (int j = 0; j < 4; ++j) o[j] = f2bf(vv[j]);
        *(usv4*)(s_bf + z * NN + e0) = o;
    } else {
        const int b = z - 32;
        float4 v = *(const float4*)(a_o + b * NN + e0);
        float vv[4] = {v.x, v.y, v.z, v.w};
        usv4 h, l;
        #pragma unroll
        for (int j = 0; j < 4; ++j) {
            unsigned short hb = f2bf(vv[j]);
            h[j] = hb;
            l[j] = f2bf(vv[j] - bf2f(hb));
        }
        *(usv4*)(Ah + b * NN + e0) = h;
        *(usv4*)(Al + b * NN + e0) = l;
    }
}

// ---- unified GEMM kernel: 512 threads (8 waves), dbuf LDS, T14 staging -----
// stage==0: grid (4,4,8)  all blocks SPLIT: AA = A@A (fp32 + hi/lo bf16 out)
// stage==1: grid (4,4,40) z<8 SPLIT: AAA = A@AA (fp32)
//                         z>=8 MIX : MIXbf[z-8] = bf16(S@A + A@S)
__global__ __launch_bounds__(512) void gemm_fused_kernel(
    const unsigned short* __restrict__ s_bf,
    const unsigned short* __restrict__ Ah, const unsigned short* __restrict__ Al,
    unsigned short* __restrict__ AAh, unsigned short* __restrict__ AAl,
    float* __restrict__ AA, float* __restrict__ AAA,
    unsigned short* __restrict__ MIXbf, int stage)
{
    const int z = blockIdx.z;
    const bool split = (stage == 0) || (z < 8);

    const unsigned short *X1, *X2, *Y1, *Y2;
    if (stage == 0)      { X1 = Ah + z * NN;  X2 = Al + z * NN;
                           Y1 = Ah + z * NN;  Y2 = Al + z * NN; }
    else if (z < 8)      { X1 = Ah + z * NN;  X2 = Al + z * NN;
                           Y1 = AAh + z * NN; Y2 = AAl + z * NN; }
    else                 { const int z2 = z - 8, b = z2 & 7;
                           X1 = s_bf + z2 * NN; X2 = Ah + b * NN;
                           Y1 = Ah + b * NN;    Y2 = s_bf + z2 * NN; }

    const int row0 = blockIdx.y * 128, col0 = blockIdx.x * 128;
    const int tid = threadIdx.x, lane = tid & 63, w = tid >> 6;   // w = 0..7
    const int wr = w >> 1, wc = w & 1;   // wave tile: 32 rows x 64 cols

    __shared__ unsigned short Xa[2][128][40], Xb[2][128][40];
    __shared__ unsigned short Ba[2][4096], Bb[2][4096];

    fv4 acc[2][4];
    #pragma unroll
    for (int mi = 0; mi < 2; ++mi)
        #pragma unroll
        for (int ni = 0; ni < 4; ++ni) acc[mi][ni] = (fv4)0.f;

    // ---- per-thread staging geometry: 1 usv8 chunk per tile per thread ----
    const int xr  = tid >> 2, xc = (tid & 3) << 3;       // X: row, col8
    const int xo  = (row0 + xr) * NDIM + xc;
    const int kl = tid & 3, hh = (tid >> 2) & 1, cs = (tid >> 3) & 7,
              kh = (tid >> 6) & 7;                       // B: conflict-free map
    const int kb  = kh * 4 + kl;                         // k 0..31
    const int yo  = kb * NDIM + col0 + cs * 16 + hh * 8;
    const int lb  = cs * 512 + kb * 16 + hh * 8;

    const unsigned laneoff = (((unsigned)lane >> 4) << 7) | (((unsigned)lane & 15) << 3);
    const unsigned wcol    = ((unsigned)wc) << 12;       // wave col half: 4 cs-blocks
    const int g4 = (lane >> 4) * 4;

    usv8 lx1, lx2, ly1, ly2;

    auto gload = [&](int k0) {
        lx1 = *(const usv8*)(X1 + xo + k0);
        lx2 = *(const usv8*)(X2 + xo + k0);
        ly1 = *(const usv8*)(Y1 + yo + k0 * NDIM);
        ly2 = *(const usv8*)(Y2 + yo + k0 * NDIM);
    };
    auto swrite = [&](int buf) {
        *(usv8*)&Xa[buf][xr][xc] = lx1;
        *(usv8*)&Xb[buf][xr][xc] = lx2;
        *(usv8*)&Ba[buf][lb] = ly1;
        *(usv8*)&Bb[buf][lb] = ly2;
    };
    auto compute = [&](int buf) {
        const unsigned ba_base = (unsigned)(uintptr_t)&Ba[buf][0];
        const unsigned bb_base = (unsigned)(uintptr_t)&Bb[buf][0];
        uv2 fa[4][2], fb[4][2];
        #pragma unroll
        for (int ni = 0; ni < 4; ++ni)
            #pragma unroll
            for (int h = 0; h < 2; ++h) {
                TRREAD(fa[ni][h], ba_base + wcol + laneoff + ni * 1024 + h * 512);
                TRREAD(fb[ni][h], bb_base + wcol + laneoff + ni * 1024 + h * 512);
            }
        asm volatile("s_waitcnt lgkmcnt(0)" ::: "memory");
        __builtin_amdgcn_sched_barrier(0);

        #pragma unroll
        for (int mi = 0; mi < 2; ++mi) {
            const unsigned short* xr1 = &Xa[buf][wr * 32 + mi * 16 + (lane & 15)][0];
            const unsigned short* xr2 = &Xb[buf][wr * 32 + mi * 16 + (lane & 15)][0];
            uv2 a0 = *(const uv2*)(xr1 + g4);
            uv2 a1 = *(const uv2*)(xr1 + 16 + g4);
            uv2 b0 = *(const uv2*)(xr2 + g4);
            uv2 b1 = *(const uv2*)(xr2 + 16 + g4);
            uv4 xva = {a0.x, a0.y, a1.x, a1.y};
            uv4 xvb = {b0.x, b0.y, b1.x, b1.y};
            #pragma unroll
            for (int ni = 0; ni < 4; ++ni) {
                uv4 vba = {fa[ni][0].x, fa[ni][0].y, fa[ni][1].x, fa[ni][1].y};
                uv4 vbb = {fb[ni][0].x, fb[ni][0].y, fb[ni][1].x, fb[ni][1].y};
                if (split) {
                    MFMA16(acc[mi][ni], xva, vba);   // hi*hi
                    MFMA16(acc[mi][ni], xva, vbb);   // hi*lo
                    MFMA16(acc[mi][ni], xvb, vba);   // lo*hi
                } else {
                    MFMA16(acc[mi][ni], xva, vba);   // S@A
                    MFMA16(acc[mi][ni], xvb, vbb);   // A@S
                }
            }
        }
    };

    // ---- 2-phase pipeline: one barrier per K-step ----
    gload(0);
    swrite(0);
    __syncthreads();
    int cur = 0;
    for (int t = 0; t < 15; ++t) {
        gload((t + 1) * 32);     // issue early (T14): latency hides under compute
        compute(cur);
        swrite(cur ^ 1);         // vmcnt drain happens here, after compute
        __syncthreads();         // single barrier: writers touched the idle buffer
        cur ^= 1;
    }
    compute(cur);

    const int g = lane >> 4, c15 = lane & 15;
    if (split) {
        float* C = (stage == 0) ? (AA + z * NN) : (AAA + z * NN);
        #pragma unroll
        for (int mi = 0; mi < 2; ++mi)
            #pragma unroll
            for (int ni = 0; ni < 4; ++ni) {
                int r = row0 + wr * 32 + mi * 16 + g * 4;
                int c = col0 + wc * 64 + ni * 16 + c15;
                #pragma unroll
                for (int q = 0; q < 4; ++q) {
                    float v = acc[mi][ni][q];
                    C[(r + q) * NDIM + c] = v;
                    if (stage == 0) {
                        unsigned short hb = f2bf(v);
                        AAh[z * NN + (r + q) * NDIM + c] = hb;
                        AAl[z * NN + (r + q) * NDIM + c] = f2bf(v - bf2f(hb));
                    }
                }
            }
    } else {
        unsigned short* Cm = MIXbf + (z - 8) * NN;
        #pragma unroll
        for (int mi = 0; mi < 2; ++mi)
            #pragma unroll
            for (int ni = 0; ni < 4; ++ni) {
                int r = row0 + wr * 32 + mi * 16 + g * 4;
                int c = col0 + wc * 64 + ni * 16 + c15;
                #pragma unroll
                for (int q = 0; q < 4; ++q)
                    Cm[(r + q) * NDIM + c] = f2bf(acc[mi][ni][q]);
            }
    }
}

// ---------------- Combine: temp[o,b,n,m] + per-(o,b) max-abs ----------------
// 8 elems/thread, grid (128, 8). use_tmp: store bf16 pre-norm tmp, else fp32 out.
__global__ __launch_bounds__(256) void combine_kernel(
    const unsigned short* __restrict__ s_bf, const unsigned short* __restrict__ Ah,
    const float* __restrict__ AA, const float* __restrict__ AAA,
    const unsigned short* __restrict__ MIXbf,
    const float* __restrict__ alpha, const float* __restrict__ beta,
    const float* __restrict__ coeffs,
    float* __restrict__ out, unsigned short* __restrict__ tmp,
    unsigned int* __restrict__ smax, int use_tmp)
{
    const int b  = blockIdx.y;
    const int e0 = blockIdx.x * 2048 + threadIdx.x * 8;
    const int n  = e0 >> 9;
    const int m0 = e0 & 511;

    float ca[8], cb[8], cc[8];
    #pragma unroll
    for (int o = 0; o < 8; ++o) {
        float c1 = 0.f, c2 = 0.f, c3 = 0.f;
        #pragma unroll
        for (int i = 0; i < 4; ++i) {
            c1 += coeffs[o * 16 + 4 + i];
            c2 += coeffs[o * 16 + 8 + i];
            c3 += coeffs[o * 16 + 12 + i];
        }
        ca[o] = c1 - 3.f * c3; cb[o] = 2.f * c2; cc[o] = 4.f * c3;
    }

    float av[8], aav[8], aaav[8], sv[4][8], mv[4][8];
    {
        usv8 a8 = *(const usv8*)(Ah + b * NN + e0);
        #pragma unroll
        for (int j = 0; j < 8; ++j) av[j] = bf2f(a8[j]);
        const float4 q0 = *(const float4*)(AA + b * NN + e0);
        const float4 q1 = *(const float4*)(AA + b * NN + e0 + 4);
        aav[0]=q0.x; aav[1]=q0.y; aav[2]=q0.z; aav[3]=q0.w;
        aav[4]=q1.x; aav[5]=q1.y; aav[6]=q1.z; aav[7]=q1.w;
        const float4 r0 = *(const float4*)(AAA + b * NN + e0);
        const float4 r1 = *(const float4*)(AAA + b * NN + e0 + 4);
        aaav[0]=r0.x; aaav[1]=r0.y; aaav[2]=r0.z; aaav[3]=r0.w;
        aaav[4]=r1.x; aaav[5]=r1.y; aaav[6]=r1.z; aaav[7]=r1.w;
        #pragma unroll
        for (int i = 0; i < 4; ++i) {
            usv8 s8 = *(const usv8*)(s_bf + (i * 8 + b) * NN + e0);
            usv8 m8 = *(const usv8*)(MIXbf + (i * 8 + b) * NN + e0);
            #pragma unroll
            for (int j = 0; j < 8; ++j) { sv[i][j] = bf2f(s8[j]); mv[i][j] = bf2f(m8[j]); }
        }
    }

    float lmax[8];
    #pragma unroll
    for (int o = 0; o < 8; ++o) {
        float outv[8];
        float lm = 0.f;
        #pragma unroll
        for (int j = 0; j < 8; ++j) {
            float t = ca[o] * av[j] + cb[o] * aav[j] + cc[o] * aaav[j];
            #pragma unroll
            for (int i = 0; i < 4; ++i)
                t += alpha[o * 4 + i] * sv[i][j] + beta[o * 4 + i] * mv[i][j];
            t *= 0.25f;
            if (n == m0 + j) t = 0.f;
            outv[j] = t;
            lm = fmaxf(lm, fabsf(t));
        }
        lmax[o] = lm;
        if (use_tmp) {
            usv8 ov;
            #pragma unroll
            for (int j = 0; j < 8; ++j) ov[j] = f2bf(outv[j]);
            *(usv8*)(tmp + (o * 8 + b) * NN + e0) = ov;
        } else {
            *(float4*)(out + (o * 8 + b) * NN + e0) =
                make_float4(outv[0], outv[1], outv[2], outv[3]);
            *(float4*)(out + (o * 8 + b) * NN + e0 + 4) =
                make_float4(outv[4], outv[5], outv[6], outv[7]);
        }
    }

    #pragma unroll
    for (int o = 0; o < 8; ++o) {
        #pragma unroll
        for (int off = 32; off > 0; off >>= 1)
            lmax[o] = fmaxf(lmax[o], __shfl_xor(lmax[o], off, 64));
    }
    __shared__ float red[4][8];
    const int lane = threadIdx.x & 63, wv = threadIdx.x >> 6;
    if (lane == 0) {
        #pragma unroll
        for (int o = 0; o < 8; ++o) red[wv][o] = lmax[o];
    }
    __syncthreads();
    if (threadIdx.x < 8) {
        const int o = threadIdx.x;
        const float mfin = fmaxf(fmaxf(red[0][o], red[1][o]), fmaxf(red[2][o], red[3][o]));
        atomicMax(&smax[o * 8 + b], __float_as_uint(mfin));
    }
}

// ---------------- Normalize + relu -> fp32 out ----------------
// 8 elems/thread, grid (128, 64)
__global__ __launch_bounds__(256) void norm_kernel(
    float* __restrict__ out, const unsigned short* __restrict__ tmp,
    const unsigned int* __restrict__ smax, const float* __restrict__ tau,
    int use_tmp)
{
    const int ob = blockIdx.y;
    const float mx = __uint_as_float(smax[ob]);
    const float inv = (mx == 0.f) ? 1.f : (1.f / mx);
    const float t = tau[ob >> 3];
    const int e0 = blockIdx.x * 2048 + threadIdx.x * 8;
    float v[8];
    if (use_tmp) {
        usv8 tv = *(const usv8*)(tmp + ob * NN + e0);
        #pragma unroll
        for (int j = 0; j < 8; ++j) v[j] = bf2f(tv[j]);
    } else {
        float4 v0 = *(float4*)(out + ob * NN + e0);
        float4 v1 = *(float4*)(out + ob * NN + e0 + 4);
        v[0]=v0.x; v[1]=v0.y; v[2]=v0.z; v[3]=v0.w;
        v[4]=v1.x; v[5]=v1.y; v[6]=v1.z; v[7]=v1.w;
    }
    #pragma unroll
    for (int j = 0; j < 8; ++j) v[j] = fmaxf(fmaf(v[j], inv, -t), 0.f);
    *(float4*)(out + ob * NN + e0)     = make_float4(v[0], v[1], v[2], v[3]);
    *(float4*)(out + ob * NN + e0 + 4) = make_float4(v[4], v[5], v[6], v[7]);
}

extern "C" void kernel_launch(void* const* d_in, const int* in_sizes, int n_in,
                              void* d_out, int out_size, void* d_ws, size_t ws_size,
                              hipStream_t stream) {
    (void)in_sizes; (void)n_in; (void)out_size;
    const float* s_in   = (const float*)d_in[0];  // (4,8,512,512)
    const float* a_o    = (const float*)d_in[1];  // (8,512,512)
    const float* alpha  = (const float*)d_in[2];  // (8,4)
    const float* beta   = (const float*)d_in[3];  // (8,4)
    const float* coeffs = (const float*)d_in[4];  // (8,4,4)
    const float* tau    = (const float*)d_in[5];  // (8)
    float* out = (float*)d_out;                   // (8,8,512,512)

    // workspace layout (r8 layout, s_bf restored)
    float* AA  = (float*)d_ws;                       // 8NN f32
    float* AAA = AA + 8 * NN;                        // 8NN f32
    unsigned short* s_bf  = (unsigned short*)(AAA + 8 * NN);  // 32NN bf16
    unsigned short* Ah    = s_bf + 32 * NN;          // 8NN
    unsigned short* Al    = Ah + 8 * NN;             // 8NN
    unsigned short* AAh   = Al + 8 * NN;             // 8NN
    unsigned short* AAl   = AAh + 8 * NN;            // 8NN
    unsigned short* MIXbf = AAl + 8 * NN;            // 32NN
    unsigned int* SMAX = (unsigned int*)(MIXbf + 32 * NN);    // 64
    unsigned short* TMP = (unsigned short*)(SMAX + 64);       // 64NN (optional)

    const size_t need_tmp = (size_t)((char*)(TMP + 64 * NN) - (char*)d_ws);
    const int use_tmp = (ws_size >= need_tmp) ? 1 : 0;

    hipLaunchKernelGGL(preconv_kernel, dim3(256, 40), dim3(256), 0, stream,
                       s_in, a_o, s_bf, Ah, Al);
    hipLaunchKernelGGL(gemm_fused_kernel, dim3(4, 4, 8), dim3(512), 0, stream,
                       s_bf, Ah, Al, AAh, AAl, AA, AAA, MIXbf, 0);   // AA
    hipLaunchKernelGGL(gemm_fused_kernel, dim3(4, 4, 40), dim3(512), 0, stream,
                       s_bf, Ah, Al, AAh, AAl, AA, AAA, MIXbf, 1);   // AAA + MIX
    hipMemsetAsync(SMAX, 0, 64 * sizeof(unsigned int), stream);
    hipLaunchKernelGGL(combine_kernel, dim3(128, 8), dim3(256), 0, stream,
                       s_bf, Ah, AA, AAA, MIXbf, alpha, beta, coeffs,
                       out, TMP, SMAX, use_tmp);
    hipLaunchKernelGGL(norm_kernel, dim3(128, 64), dim3(256), 0, stream,
                       out, TMP, SMAX, tau, use_tmp);
}